// Round 15
// baseline (634.397 us; speedup 1.0000x reference)
//
#include <hip/hip_runtime.h>
#include <hip/hip_bf16.h>
#include <cstdint>
#include <cstddef>

#define DIMC 1024
#define HEADS 16
#define HD 64
#define DFF 4096
#define BB 4
#define SS 4096
#define NROWS (BB*SS)   // 16384

typedef __bf16 bf16_t;
typedef __bf16 bf16x8 __attribute__((ext_vector_type(8)));
typedef __bf16 bf16x4 __attribute__((ext_vector_type(4)));
typedef float  f32x4  __attribute__((ext_vector_type(4)));

#define GLDS16(gp, lp) \
  __builtin_amdgcn_global_load_lds((const __attribute__((address_space(1))) void*)(gp), \
                                   (__attribute__((address_space(3))) void*)(lp), 16, 0, 0)

#define MFMA16(a, b, c) __builtin_amdgcn_mfma_f32_16x16x32_bf16((a), (b), (c), 0, 0, 0)

// fast erf, Abramowitz-Stegun 7.1.26, |abs err| <= 1.5e-7
__device__ __forceinline__ float fast_erf(float x) {
  float ax = fabsf(x);
  float t  = __builtin_amdgcn_rcpf(fmaf(0.3275911f, ax, 1.0f));
  float p  = t * fmaf(t, fmaf(t, fmaf(t, fmaf(t, 1.061405429f, -1.453152027f),
                                      1.421413741f), -0.284496736f), 0.254829592f);
  float er = 1.0f - p * __expf(-ax * ax);
  return copysignf(er, x);
}

// ---------------------------------------------------------------- fused prep: 4x weight transpose + ln1
// blocks [0,12288): W transposes (f32[K][N] -> bf16[N][K], 32x32 tiles)
// blocks [12288, 28672): ln1 rows
__global__ __launch_bounds__(256) void prep_kernel(const float* __restrict__ w_qkv,
                                                   const float* __restrict__ w_out,
                                                   const float* __restrict__ w_ffn1,
                                                   const float* __restrict__ w_ffn2,
                                                   bf16_t* __restrict__ WT_QKV,
                                                   bf16_t* __restrict__ WT_OUT,
                                                   bf16_t* __restrict__ WT_FFN1,
                                                   bf16_t* __restrict__ WT_FFN2,
                                                   const float* __restrict__ x,
                                                   const float* __restrict__ gamma,
                                                   const float* __restrict__ beta,
                                                   bf16_t* __restrict__ act1) {
  const int bid = blockIdx.x;
  if (bid < 12288) {
    const float* W; bf16_t* Wt; int K, N, bx, by;
    if (bid < 3072)      { W = w_qkv;  Wt = WT_QKV;  K = 1024; N = 3072; bx = bid % 96;           by = bid / 96; }
    else if (bid < 4096) { W = w_out;  Wt = WT_OUT;  K = 1024; N = 1024; bx = (bid - 3072) % 32;  by = (bid - 3072) / 32; }
    else if (bid < 8192) { W = w_ffn1; Wt = WT_FFN1; K = 1024; N = 4096; bx = (bid - 4096) % 128; by = (bid - 4096) / 128; }
    else                 { W = w_ffn2; Wt = WT_FFN2; K = 4096; N = 1024; bx = (bid - 8192) % 32;  by = (bid - 8192) / 32; }
    __shared__ float tile[32][33];
    const int tx = threadIdx.x & 31, ty = threadIdx.x >> 5;   // 32 x 8
    const int c0 = bx * 32, r0 = by * 32;
    #pragma unroll
    for (int i = 0; i < 32; i += 8)
      tile[ty + i][tx] = W[(long)(r0 + ty + i) * N + c0 + tx];
    __syncthreads();
    #pragma unroll
    for (int i = 0; i < 32; i += 8)
      Wt[(long)(c0 + ty + i) * K + r0 + tx] = (bf16_t)tile[tx][ty + i];
  } else {
    long r = bid - 12288;
    int t = threadIdx.x;
    float4 v = ((const float4*)(x + r * DIMC))[t];
    float s  = v.x + v.y + v.z + v.w;
    float sq = v.x * v.x + v.y * v.y + v.z * v.z + v.w * v.w;
    #pragma unroll
    for (int o = 32; o > 0; o >>= 1) { s += __shfl_xor(s, o); sq += __shfl_xor(sq, o); }
    __shared__ float red[8];
    if ((t & 63) == 0) { red[(t >> 6) * 2] = s; red[(t >> 6) * 2 + 1] = sq; }
    __syncthreads();
    s  = red[0] + red[2] + red[4] + red[6];
    sq = red[1] + red[3] + red[5] + red[7];
    float mu  = s * (1.0f / DIMC);
    float var = sq * (1.0f / DIMC) - mu * mu;
    float rs  = 1.0f / sqrtf(var + 1e-5f);
    float4 g  = ((const float4*)gamma)[t];
    float4 bb = ((const float4*)beta)[t];
    bf16x4 o;
    o[0] = (bf16_t)((v.x - mu) * rs * g.x + bb.x);
    o[1] = (bf16_t)((v.y - mu) * rs * g.y + bb.y);
    o[2] = (bf16_t)((v.z - mu) * rs * g.z + bb.z);
    o[3] = (bf16_t)((v.w - mu) * rs * g.w + bb.w);
    ((bf16x4*)(act1 + r * DIMC))[t] = o;
  }
}

// ---------------------------------------------------------------- LayerNorm f32 row -> bf16 row (standalone, for ln2)
__global__ __launch_bounds__(256) void ln_kernel(const float* __restrict__ in,
                                                 const float* __restrict__ gamma,
                                                 const float* __restrict__ beta,
                                                 bf16_t* __restrict__ out) {
  long r = blockIdx.x;
  int t = threadIdx.x;
  float4 v = ((const float4*)(in + r * DIMC))[t];
  float s  = v.x + v.y + v.z + v.w;
  float sq = v.x * v.x + v.y * v.y + v.z * v.z + v.w * v.w;
  #pragma unroll
  for (int o = 32; o > 0; o >>= 1) { s += __shfl_xor(s, o); sq += __shfl_xor(sq, o); }
  __shared__ float red[8];
  if ((t & 63) == 0) { red[(t >> 6) * 2] = s; red[(t >> 6) * 2 + 1] = sq; }
  __syncthreads();
  s  = red[0] + red[2] + red[4] + red[6];
  sq = red[1] + red[3] + red[5] + red[7];
  float mu  = s * (1.0f / DIMC);
  float var = sq * (1.0f / DIMC) - mu * mu;
  float rs  = 1.0f / sqrtf(var + 1e-5f);
  float4 g  = ((const float4*)gamma)[t];
  float4 bb = ((const float4*)beta)[t];
  bf16x4 o;
  o[0] = (bf16_t)((v.x - mu) * rs * g.x + bb.x);
  o[1] = (bf16_t)((v.y - mu) * rs * g.y + bb.y);
  o[2] = (bf16_t)((v.z - mu) * rs * g.z + bb.z);
  o[3] = (bf16_t)((v.w - mu) * rs * g.w + bb.w);
  ((bf16x4*)(out + r * DIMC))[t] = o;
}

// ---------------------------------------------------------------- GEMM: A[M][K] bf16 @ Bt[N][K] bf16 -> epilogue
// 128x128 tile, BK=64, XCD swizzle, XOR LDS swizzle (conflict-free), multi-block/CU.
// MODE 0: bf16 = acc+bias     MODE 1: f32 = acc+bias+resid
// MODE 2: bf16 = gelu(acc+bias) (fast erf)
// MODE 3: bf16 = acc+bias, with per-(row,head) softmax fused for cols < 1024 (Q region)
template <int MODE>
__global__ __launch_bounds__(256, 2) void gemm_bt(const bf16_t* __restrict__ A,
                                                  const bf16_t* __restrict__ Bt,
                                                  const float* __restrict__ bias,
                                                  const float* __restrict__ resid,
                                                  void* __restrict__ outp,
                                                  int M, int N, int K) {
  __shared__ bf16_t As[128 * 64];
  __shared__ bf16_t Bs[128 * 64];
  const int t = threadIdx.x;
  const int lane = t & 63;
  const int wave = t >> 6;

  // T1: bijective XCD swizzle (all nwg here %8==0, gridDim.x %4==0) + 8-row x 4-col grouping
  const int nwg  = gridDim.x * gridDim.y;
  const int bid0 = blockIdx.y * gridDim.x + blockIdx.x;
  const int lg   = (bid0 & 7) * (nwg >> 3) + (bid0 >> 3);
  const int span = (int)gridDim.y << 2;
  const int gidx = lg / span;
  const int rem  = lg - gidx * span;
  const long arow0 = (long)(rem >> 2) * 128;
  const long brow0 = (long)((gidx << 2) + (rem & 3)) * 128;

  const int wm = (wave >> 1) * 64, wn = (wave & 1) * 64;

  f32x4 acc[4][4] = {};
  const int fr  = lane & 15;
  const int q4  = lane >> 4;
  const int frl = fr & 7;
  const int cr0 = ((q4    ) ^ frl) * 8;   // element offset of k-half-0 chunk
  const int cr1 = ((q4 + 4) ^ frl) * 8;   // element offset of k-half-1 chunk

  for (int kt = 0; kt < K; kt += 64) {
    #pragma unroll
    for (int p = 0; p < 4; ++p) {
      const int c = t + 256 * p;
      const int row = c >> 3;
      const int gch = ((c & 7) ^ (row & 7)) * 8;   // source chunk XOR'd; dest linear (rule #21)
      GLDS16(A  + (arow0 + row) * K + kt + gch, &As[c * 8]);
      GLDS16(Bt + (brow0 + row) * K + kt + gch, &Bs[c * 8]);
    }
    asm volatile("s_waitcnt vmcnt(0)" ::: "memory");
    __syncthreads();
    {
      bf16x8 a[4], b[4];
      #pragma unroll
      for (int i = 0; i < 4; ++i) {
        a[i] = *(const bf16x8*)&As[(wm + i * 16 + fr) * 64 + cr0];
        b[i] = *(const bf16x8*)&Bs[(wn + i * 16 + fr) * 64 + cr0];
      }
      #pragma unroll
      for (int i = 0; i < 4; ++i)
        #pragma unroll
        for (int j = 0; j < 4; ++j)
          acc[i][j] = MFMA16(a[i], b[j], acc[i][j]);
      #pragma unroll
      for (int i = 0; i < 4; ++i) {
        a[i] = *(const bf16x8*)&As[(wm + i * 16 + fr) * 64 + cr1];
        b[i] = *(const bf16x8*)&Bs[(wn + i * 16 + fr) * 64 + cr1];
      }
      #pragma unroll
      for (int i = 0; i < 4; ++i)
        #pragma unroll
        for (int j = 0; j < 4; ++j)
          acc[i][j] = MFMA16(a[i], b[j], acc[i][j]);
    }
    __syncthreads();
  }

  const int rq = q4 * 4;

  if (MODE == 3 && brow0 < 1024) {
    // fused q-softmax: each row's 64 head-cols live in lanes fr=0..15 (q4 fixed) x 4 j-regs
    float bv[4];
    #pragma unroll
    for (int j = 0; j < 4; ++j) bv[j] = bias[brow0 + wn + j * 16 + fr];
    #pragma unroll
    for (int i = 0; i < 4; ++i) {
      #pragma unroll
      for (int r = 0; r < 4; ++r) {
        float v[4];
        #pragma unroll
        for (int j = 0; j < 4; ++j) v[j] = acc[i][j][r] + bv[j];
        float m = fmaxf(fmaxf(v[0], v[1]), fmaxf(v[2], v[3]));
        #pragma unroll
        for (int o = 1; o <= 8; o <<= 1) m = fmaxf(m, __shfl_xor(m, o));
        float e[4], s = 0.f;
        #pragma unroll
        for (int j = 0; j < 4; ++j) { e[j] = __expf(v[j] - m); s += e[j]; }
        #pragma unroll
        for (int o = 1; o <= 8; o <<= 1) s += __shfl_xor(s, o);
        float inv = 1.0f / s;
        long row = arow0 + wm + i * 16 + rq + r;
        #pragma unroll
        for (int j = 0; j < 4; ++j)
          ((bf16_t*)outp)[row * N + brow0 + wn + j * 16 + fr] = (bf16_t)(e[j] * inv);
      }
    }
  } else {
    #pragma unroll
    for (int i = 0; i < 4; ++i) {
      #pragma unroll
      for (int j = 0; j < 4; ++j) {
        long col = brow0 + wn + j * 16 + fr;
        float bv = bias[col];
        #pragma unroll
        for (int r = 0; r < 4; ++r) {
          long row = arow0 + wm + i * 16 + rq + r;
          float v = acc[i][j][r] + bv;
          if (MODE == 0 || MODE == 3) {
            ((bf16_t*)outp)[row * N + col] = (bf16_t)v;
          } else if (MODE == 1) {
            ((float*)outp)[row * N + col] = v + resid[row * N + col];
          } else {
            float g = 0.5f * v * (1.0f + fast_erf(v * 0.70710678118654752f));
            ((bf16_t*)outp)[row * N + col] = (bf16_t)g;
          }
        }
      }
    }
  }
}

// ---------------------------------------------------------------- kv partials WITH fused exp + column-sum.
// No max subtraction: k ~ N(0,1), exp safe in f32. V held in LDS as f32 (no per-FMA converts).
__global__ __launch_bounds__(256) void kv_partial(const bf16_t* __restrict__ qkv,
                                                  float* __restrict__ kvp,
                                                  float* __restrict__ esump) {
  int bh = blockIdx.x, ch = blockIdx.y;
  int b = bh >> 4, h = bh & 15;
  int t = threadIdx.x;
  __shared__ float Kexp[64][65];
  __shared__ float Vs[64][66];
  int rowl = t >> 2, c0 = (t & 3) * 16;
  int dd = t >> 2, e0 = (t & 3) * 16;
  int lsq = (t & 3) * 16;               // this thread's esum ls-quarter
  float acc[16] = {};
  float esum = 0.f;
  for (int sb = 0; sb < 8; ++sb) {
    long s = (long)ch * 512 + sb * 64 + rowl;
    const bf16_t* base = qkv + ((long)b * SS + s) * 3072 + h * 64;
    bf16x8 k0 = *(const bf16x8*)(base + 1024 + c0);
    bf16x8 k1 = *(const bf16x8*)(base + 1024 + c0 + 8);
    bf16x8 v0 = *(const bf16x8*)(base + 2048 + c0);
    bf16x8 v1 = *(const bf16x8*)(base + 2048 + c0 + 8);
    __syncthreads();
    #pragma unroll
    for (int j = 0; j < 8; ++j) {
      Kexp[rowl][c0 + j]     = __expf((float)k0[j]);
      Kexp[rowl][c0 + 8 + j] = __expf((float)k1[j]);
      Vs[rowl][c0 + j]       = (float)v0[j];
      Vs[rowl][c0 + 8 + j]   = (float)v1[j];
    }
    __syncthreads();
    for (int ls = 0; ls < 64; ++ls) {
      float kd = Kexp[ls][dd];
      f32x4 va0 = *(const f32x4*)&Vs[ls][e0];
      f32x4 va1 = *(const f32x4*)&Vs[ls][e0 + 4];
      f32x4 va2 = *(const f32x4*)&Vs[ls][e0 + 8];
      f32x4 va3 = *(const f32x4*)&Vs[ls][e0 + 12];
      #pragma unroll
      for (int j = 0; j < 4; ++j) {
        acc[j]      += kd * va0[j];
        acc[j + 4]  += kd * va1[j];
        acc[j + 8]  += kd * va2[j];
        acc[j + 12] += kd * va3[j];
      }
    }
    #pragma unroll
    for (int l2 = 0; l2 < 16; ++l2) esum += Kexp[lsq + l2][dd];
  }
  float* dst = kvp + (long)(bh * 8 + ch) * 4096 + dd * 64 + e0;
  #pragma unroll
  for (int j = 0; j < 16; ++j) dst[j] = acc[j];
  // fold the 4 quarter-partials (threads dd*4 .. dd*4+3, consecutive lanes)
  esum += __shfl_xor(esum, 1);
  esum += __shfl_xor(esum, 2);
  if ((t & 3) == 0) esump[(long)(bh * 8 + ch) * 64 + dd] = esum;
}

// reduce partials + normalize, store TRANSPOSED bf16: kvT[bh][e][d]
__global__ void kv_reduce(const float* __restrict__ kvp, const float* __restrict__ esump,
                          bf16_t* __restrict__ kvT) {
  int bh = blockIdx.x, t = threadIdx.x;
  __shared__ float ei[64];
  if (t < 64) {
    float es = 0.f;
    #pragma unroll
    for (int c = 0; c < 8; ++c) es += esump[(long)(bh * 8 + c) * 64 + t];
    ei[t] = 1.0f / es;
  }
  __syncthreads();
  for (int p = t; p < 4096; p += 256) {
    int d = p >> 6, e = p & 63;
    float s = 0.f;
    #pragma unroll
    for (int c = 0; c < 8; ++c) s += kvp[(long)(bh * 8 + c) * 4096 + p];
    kvT[(long)bh * 4096 + e * 64 + d] = (bf16_t)(s * ei[d]);
  }
}

// ---------------------------------------------------------------- out[s,e] = q_sm[s,:] @ kv[:,e]  via MFMA, per (b,h)
__global__ __launch_bounds__(256) void attn_apply(const bf16_t* __restrict__ qkv,
                                                  const bf16_t* __restrict__ kvT,
                                                  bf16_t* __restrict__ attn) {
  int bh = blockIdx.x, sc = blockIdx.y;
  int b = bh >> 4, h = bh & 15;
  int t = threadIdx.x, lane = t & 63, w = t >> 6;
  __shared__ bf16_t kvs[64 * 64];
  for (int i = t * 8; i < 4096; i += 256 * 8)
    *(bf16x8*)&kvs[i] = *(const bf16x8*)(kvT + (long)bh * 4096 + i);
  __syncthreads();
  int fr = lane & 15, kq = (lane >> 4) * 8;
  long qrow = (long)b * SS + sc * 128 + w * 32;
  f32x4 acc[2][4] = {};
  #pragma unroll
  for (int kk = 0; kk < 2; ++kk) {
    bf16x8 a0 = *(const bf16x8*)(qkv + (qrow + fr) * 3072      + h * 64 + kk * 32 + kq);
    bf16x8 a1 = *(const bf16x8*)(qkv + (qrow + 16 + fr) * 3072 + h * 64 + kk * 32 + kq);
    #pragma unroll
    for (int j = 0; j < 4; ++j) {
      bf16x8 bfr = *(const bf16x8*)&kvs[(j * 16 + fr) * 64 + kk * 32 + kq];
      acc[0][j] = MFMA16(a0, bfr, acc[0][j]);
      acc[1][j] = MFMA16(a1, bfr, acc[1][j]);
    }
  }
  int rq = (lane >> 4) * 4;
  #pragma unroll
  for (int i = 0; i < 2; ++i)
    #pragma unroll
    for (int j = 0; j < 4; ++j)
      #pragma unroll
      for (int r = 0; r < 4; ++r)
        attn[(qrow + i * 16 + rq + r) * 1024 + h * 64 + j * 16 + fr] = (bf16_t)acc[i][j][r];
}

// ---------------------------------------------------------------- launch
extern "C" void kernel_launch(void* const* d_in, const int* in_sizes, int n_in,
                              void* d_out, int out_size, void* d_ws, size_t ws_size,
                              hipStream_t stream) {
  (void)in_sizes; (void)n_in; (void)out_size;
  const float* x      = (const float*)d_in[0];
  const float* w_qkv  = (const float*)d_in[1];
  const float* b_qkv  = (const float*)d_in[2];
  const float* w_out  = (const float*)d_in[3];
  const float* b_out  = (const float*)d_in[4];
  const float* w_ffn1 = (const float*)d_in[5];
  const float* b_ffn1 = (const float*)d_in[6];
  const float* w_ffn2 = (const float*)d_in[7];
  const float* b_ffn2 = (const float*)d_in[8];
  const float* g1     = (const float*)d_in[9];
  const float* be1    = (const float*)d_in[10];
  const float* g2     = (const float*)d_in[11];
  const float* be2    = (const float*)d_in[12];

  char* ws = (char*)d_ws;
  constexpr size_t WT_QKV_OFF  = 0;
  constexpr size_t WT_OUT_OFF  = WT_QKV_OFF  + 6291456;
  constexpr size_t WT_FFN1_OFF = WT_OUT_OFF  + 2097152;
  constexpr size_t WT_FFN2_OFF = WT_FFN1_OFF + 8388608;
  constexpr size_t ESUMP_OFF   = WT_FFN2_OFF + 8388608;   // 512*64*4 = 131072
  constexpr size_t KVP_OFF     = ESUMP_OFF   + 294912;
  constexpr size_t KVT_OFF     = KVP_OFF     + 8388608;
  constexpr size_t ACT1_OFF    = KVT_OFF     + 524288;
  constexpr size_t BIG_OFF     = ACT1_OFF    + 33554432;  // 67,928,064

  bf16_t* WT_QKV  = (bf16_t*)(ws + WT_QKV_OFF);
  bf16_t* WT_OUT  = (bf16_t*)(ws + WT_OUT_OFF);
  bf16_t* WT_FFN1 = (bf16_t*)(ws + WT_FFN1_OFF);
  bf16_t* WT_FFN2 = (bf16_t*)(ws + WT_FFN2_OFF);
  float*  ESUMP   = (float*) (ws + ESUMP_OFF);
  float*  KVP     = (float*) (ws + KVP_OFF);
  bf16_t* KVT     = (bf16_t*)(ws + KVT_OFF);
  bf16_t* ACT1    = (bf16_t*)(ws + ACT1_OFF);
  bf16_t* QKV     = (bf16_t*)(ws + BIG_OFF);   // 96 MB
  bf16_t* GACT    = (bf16_t*)(ws + BIG_OFF);   // up to 128 MB, after QKV dead
  float*  Y       = (float*)  d_out;           // residual mid-buffer lives in d_out

  const bool big_ws = ws_size >= (size_t)(BIG_OFF + 134217728ull);

  // fused prep: all 4 weight transposes + ln1, one dispatch (independent work co-scheduled)
  prep_kernel<<<12288 + NROWS, 256, 0, stream>>>(w_qkv, w_out, w_ffn1, w_ffn2,
                                                 WT_QKV, WT_OUT, WT_FFN1, WT_FFN2,
                                                 x, g1, be1, ACT1);

  // qkv = ln1 @ WqkvT + b, q-softmax fused in epilogue (grid 24 x 128)
  gemm_bt<3><<<dim3(3072 / 128, NROWS / 128), 256, 0, stream>>>(ACT1, WT_QKV, b_qkv, nullptr, QKV, NROWS, 3072, 1024);

  // kv einsum with fused exp + column-sum (no separate stats pass)
  kv_partial<<<dim3(64, 8), 256, 0, stream>>>(QKV, KVP, ESUMP);
  kv_reduce<<<64, 256, 0, stream>>>(KVP, ESUMP, KVT);
  attn_apply<<<dim3(64, SS / 128), 256, 0, stream>>>(QKV, KVT, ACT1);

  // y = x + attn_cat @ WoutT + b  -> d_out  (grid 8 x 128)
  gemm_bt<1><<<dim3(1024 / 128, NROWS / 128), 256, 0, stream>>>(ACT1, WT_OUT, b_out, x, Y, NROWS, 1024, 1024);

  ln_kernel<<<NROWS, 256, 0, stream>>>(Y, g2, be2, ACT1);

  if (big_ws) {
    // full-width FFN: ffn1 grid 32 x 128, ffn2 grid 8 x 128
    gemm_bt<2><<<dim3(4096 / 128, NROWS / 128), 256, 0, stream>>>(ACT1, WT_FFN1, b_ffn1, nullptr, GACT, NROWS, 4096, 1024);
    gemm_bt<1><<<dim3(1024 / 128, NROWS / 128), 256, 0, stream>>>(GACT, WT_FFN2, b_ffn2, x, (float*)d_out, NROWS, 1024, 4096);
  } else {
    for (int c = 0; c < 2; ++c) {
      const long r0 = (long)c * 8192;
      gemm_bt<2><<<dim3(4096 / 128, 8192 / 128), 256, 0, stream>>>(
          ACT1 + r0 * 1024, WT_FFN1, b_ffn1, nullptr, GACT, 8192, 4096, 1024);
      gemm_bt<1><<<dim3(1024 / 128, 8192 / 128), 256, 0, stream>>>(
          GACT, WT_FFN2, b_ffn2, x + r0 * 1024, (float*)d_out + r0 * 1024, 8192, 1024, 4096);
    }
  }
}

// Round 19
// 606.631 us; speedup vs baseline: 1.0458x; 1.0458x over previous
//
#include <hip/hip_runtime.h>
#include <hip/hip_bf16.h>
#include <cstdint>
#include <cstddef>

#define DIMC 1024
#define HEADS 16
#define HD 64
#define DFF 4096
#define BB 4
#define SS 4096
#define NROWS (BB*SS)   // 16384

typedef __bf16 bf16_t;
typedef __bf16 bf16x8 __attribute__((ext_vector_type(8)));
typedef __bf16 bf16x4 __attribute__((ext_vector_type(4)));
typedef float  f32x4  __attribute__((ext_vector_type(4)));

#define GLDS16(gp, lp) \
  __builtin_amdgcn_global_load_lds((const __attribute__((address_space(1))) void*)(gp), \
                                   (__attribute__((address_space(3))) void*)(lp), 16, 0, 0)

#define MFMA16(a, b, c) __builtin_amdgcn_mfma_f32_16x16x32_bf16((a), (b), (c), 0, 0, 0)

// fast erf, Abramowitz-Stegun 7.1.26, |abs err| <= 1.5e-7
__device__ __forceinline__ float fast_erf(float x) {
  float ax = fabsf(x);
  float t  = __builtin_amdgcn_rcpf(fmaf(0.3275911f, ax, 1.0f));
  float p  = t * fmaf(t, fmaf(t, fmaf(t, fmaf(t, 1.061405429f, -1.453152027f),
                                      1.421413741f), -0.284496736f), 0.254829592f);
  float er = 1.0f - p * __expf(-ax * ax);
  return copysignf(er, x);
}

// ---------------------------------------------------------------- fused prep: 4x weight transpose + ln1
__global__ __launch_bounds__(256) void prep_kernel(const float* __restrict__ w_qkv,
                                                   const float* __restrict__ w_out,
                                                   const float* __restrict__ w_ffn1,
                                                   const float* __restrict__ w_ffn2,
                                                   bf16_t* __restrict__ WT_QKV,
                                                   bf16_t* __restrict__ WT_OUT,
                                                   bf16_t* __restrict__ WT_FFN1,
                                                   bf16_t* __restrict__ WT_FFN2,
                                                   const float* __restrict__ x,
                                                   const float* __restrict__ gamma,
                                                   const float* __restrict__ beta,
                                                   bf16_t* __restrict__ act1) {
  const int bid = blockIdx.x;
  if (bid < 12288) {
    const float* W; bf16_t* Wt; int K, N, bx, by;
    if (bid < 3072)      { W = w_qkv;  Wt = WT_QKV;  K = 1024; N = 3072; bx = bid % 96;           by = bid / 96; }
    else if (bid < 4096) { W = w_out;  Wt = WT_OUT;  K = 1024; N = 1024; bx = (bid - 3072) % 32;  by = (bid - 3072) / 32; }
    else if (bid < 8192) { W = w_ffn1; Wt = WT_FFN1; K = 1024; N = 4096; bx = (bid - 4096) % 128; by = (bid - 4096) / 128; }
    else                 { W = w_ffn2; Wt = WT_FFN2; K = 4096; N = 1024; bx = (bid - 8192) % 32;  by = (bid - 8192) / 32; }
    __shared__ float tile[32][33];
    const int tx = threadIdx.x & 31, ty = threadIdx.x >> 5;
    const int c0 = bx * 32, r0 = by * 32;
    #pragma unroll
    for (int i = 0; i < 32; i += 8)
      tile[ty + i][tx] = W[(long)(r0 + ty + i) * N + c0 + tx];
    __syncthreads();
    #pragma unroll
    for (int i = 0; i < 32; i += 8)
      Wt[(long)(c0 + ty + i) * K + r0 + tx] = (bf16_t)tile[tx][ty + i];
  } else {
    long r = bid - 12288;
    int t = threadIdx.x;
    float4 v = ((const float4*)(x + r * DIMC))[t];
    float s  = v.x + v.y + v.z + v.w;
    float sq = v.x * v.x + v.y * v.y + v.z * v.z + v.w * v.w;
    #pragma unroll
    for (int o = 32; o > 0; o >>= 1) { s += __shfl_xor(s, o); sq += __shfl_xor(sq, o); }
    __shared__ float red[8];
    if ((t & 63) == 0) { red[(t >> 6) * 2] = s; red[(t >> 6) * 2 + 1] = sq; }
    __syncthreads();
    s  = red[0] + red[2] + red[4] + red[6];
    sq = red[1] + red[3] + red[5] + red[7];
    float mu  = s * (1.0f / DIMC);
    float var = sq * (1.0f / DIMC) - mu * mu;
    float rs  = 1.0f / sqrtf(var + 1e-5f);
    float4 g  = ((const float4*)gamma)[t];
    float4 bb = ((const float4*)beta)[t];
    bf16x4 o;
    o[0] = (bf16_t)((v.x - mu) * rs * g.x + bb.x);
    o[1] = (bf16_t)((v.y - mu) * rs * g.y + bb.y);
    o[2] = (bf16_t)((v.z - mu) * rs * g.z + bb.z);
    o[3] = (bf16_t)((v.w - mu) * rs * g.w + bb.w);
    ((bf16x4*)(act1 + r * DIMC))[t] = o;
  }
}

// ---------------------------------------------------------------- LayerNorm bf16 row -> bf16 row (ln2; y stored bf16)
__global__ __launch_bounds__(256) void ln_bf16(const bf16_t* __restrict__ in,
                                               const float* __restrict__ gamma,
                                               const float* __restrict__ beta,
                                               bf16_t* __restrict__ out) {
  long r = blockIdx.x;
  int t = threadIdx.x;
  bf16x4 v4 = ((const bf16x4*)(in + r * DIMC))[t];
  float v0 = v4[0], v1 = v4[1], v2 = v4[2], v3 = v4[3];
  float s  = v0 + v1 + v2 + v3;
  float sq = v0 * v0 + v1 * v1 + v2 * v2 + v3 * v3;
  #pragma unroll
  for (int o = 32; o > 0; o >>= 1) { s += __shfl_xor(s, o); sq += __shfl_xor(sq, o); }
  __shared__ float red[8];
  if ((t & 63) == 0) { red[(t >> 6) * 2] = s; red[(t >> 6) * 2 + 1] = sq; }
  __syncthreads();
  s  = red[0] + red[2] + red[4] + red[6];
  sq = red[1] + red[3] + red[5] + red[7];
  float mu  = s * (1.0f / DIMC);
  float var = sq * (1.0f / DIMC) - mu * mu;
  float rs  = 1.0f / sqrtf(var + 1e-5f);
  float4 g  = ((const float4*)gamma)[t];
  float4 bb = ((const float4*)beta)[t];
  bf16x4 o;
  o[0] = (bf16_t)((v0 - mu) * rs * g.x + bb.x);
  o[1] = (bf16_t)((v1 - mu) * rs * g.y + bb.y);
  o[2] = (bf16_t)((v2 - mu) * rs * g.z + bb.z);
  o[3] = (bf16_t)((v3 - mu) * rs * g.w + bb.w);
  ((bf16x4*)(out + r * DIMC))[t] = o;
}

// ---------------------------------------------------------------- GEMM: A[M][K](lda) bf16 @ Bt[N][K] bf16 -> epilogue
// 128x128 tile, BK=64, XCD swizzle, XOR LDS swizzle (conflict-free), multi-block/CU.
// Bt may be per-batch (bstride elements per 4096 A-rows).
// MODE 0: bf16 = acc+bias                MODE 1: f32  = acc+bias+resid(f32)
// MODE 2: bf16 = gelu(acc+bias)          MODE 3: bf16 = acc+bias, q-softmax fused for cols<1024
// MODE 4: bf16 = acc+bias+resid(f32)
template <int MODE>
__global__ __launch_bounds__(256, 2) void gemm_bt(const bf16_t* __restrict__ A,
                                                  const bf16_t* __restrict__ Bt,
                                                  const float* __restrict__ bias,
                                                  const float* __restrict__ resid,
                                                  void* __restrict__ outp,
                                                  int M, int N, int K, int lda, long bstride) {
  __shared__ bf16_t As[128 * 64];
  __shared__ bf16_t Bs[128 * 64];
  const int t = threadIdx.x;
  const int lane = t & 63;
  const int wave = t >> 6;

  const int nwg  = gridDim.x * gridDim.y;
  const int bid0 = blockIdx.y * gridDim.x + blockIdx.x;
  const int lg   = (bid0 & 7) * (nwg >> 3) + (bid0 >> 3);
  const int span = (int)gridDim.y << 2;
  const int gidx = lg / span;
  const int rem  = lg - gidx * span;
  const long arow0 = (long)(rem >> 2) * 128;
  const long brow0 = (long)((gidx << 2) + (rem & 3)) * 128;

  const bf16_t* BtB = Bt + (arow0 >> 12) * bstride;

  const int wm = (wave >> 1) * 64, wn = (wave & 1) * 64;

  f32x4 acc[4][4] = {};
  const int fr  = lane & 15;
  const int q4  = lane >> 4;
  const int frl = fr & 7;
  const int cr0 = ((q4    ) ^ frl) * 8;
  const int cr1 = ((q4 + 4) ^ frl) * 8;

  for (int kt = 0; kt < K; kt += 64) {
    #pragma unroll
    for (int p = 0; p < 4; ++p) {
      const int c = t + 256 * p;
      const int row = c >> 3;
      const int gch = ((c & 7) ^ (row & 7)) * 8;
      GLDS16(A   + (arow0 + row) * (long)lda + kt + gch, &As[c * 8]);
      GLDS16(BtB + (brow0 + row) * (long)K   + kt + gch, &Bs[c * 8]);
    }
    asm volatile("s_waitcnt vmcnt(0)" ::: "memory");
    __syncthreads();
    {
      bf16x8 a[4], b[4];
      #pragma unroll
      for (int i = 0; i < 4; ++i) {
        a[i] = *(const bf16x8*)&As[(wm + i * 16 + fr) * 64 + cr0];
        b[i] = *(const bf16x8*)&Bs[(wn + i * 16 + fr) * 64 + cr0];
      }
      #pragma unroll
      for (int i = 0; i < 4; ++i)
        #pragma unroll
        for (int j = 0; j < 4; ++j)
          acc[i][j] = MFMA16(a[i], b[j], acc[i][j]);
      #pragma unroll
      for (int i = 0; i < 4; ++i) {
        a[i] = *(const bf16x8*)&As[(wm + i * 16 + fr) * 64 + cr1];
        b[i] = *(const bf16x8*)&Bs[(wn + i * 16 + fr) * 64 + cr1];
      }
      #pragma unroll
      for (int i = 0; i < 4; ++i)
        #pragma unroll
        for (int j = 0; j < 4; ++j)
          acc[i][j] = MFMA16(a[i], b[j], acc[i][j]);
    }
    __syncthreads();
  }

  const int rq = q4 * 4;

  if (MODE == 3 && brow0 < 1024) {
    float bv[4];
    #pragma unroll
    for (int j = 0; j < 4; ++j) bv[j] = bias[brow0 + wn + j * 16 + fr];
    #pragma unroll
    for (int i = 0; i < 4; ++i) {
      #pragma unroll
      for (int r = 0; r < 4; ++r) {
        float v[4];
        #pragma unroll
        for (int j = 0; j < 4; ++j) v[j] = acc[i][j][r] + bv[j];
        float m = fmaxf(fmaxf(v[0], v[1]), fmaxf(v[2], v[3]));
        #pragma unroll
        for (int o = 1; o <= 8; o <<= 1) m = fmaxf(m, __shfl_xor(m, o));
        float e[4], s = 0.f;
        #pragma unroll
        for (int j = 0; j < 4; ++j) { e[j] = __expf(v[j] - m); s += e[j]; }
        #pragma unroll
        for (int o = 1; o <= 8; o <<= 1) s += __shfl_xor(s, o);
        float inv = 1.0f / s;
        long row = arow0 + wm + i * 16 + rq + r;
        #pragma unroll
        for (int j = 0; j < 4; ++j)
          ((bf16_t*)outp)[row * N + brow0 + wn + j * 16 + fr] = (bf16_t)(e[j] * inv);
      }
    }
  } else {
    #pragma unroll
    for (int i = 0; i < 4; ++i) {
      #pragma unroll
      for (int j = 0; j < 4; ++j) {
        long col = brow0 + wn + j * 16 + fr;
        float bv = bias[col];
        #pragma unroll
        for (int r = 0; r < 4; ++r) {
          long row = arow0 + wm + i * 16 + rq + r;
          float v = acc[i][j][r] + bv;
          if (MODE == 0 || MODE == 3) {
            ((bf16_t*)outp)[row * N + col] = (bf16_t)v;
          } else if (MODE == 1) {
            ((float*)outp)[row * N + col] = v + resid[row * N + col];
          } else if (MODE == 4) {
            ((bf16_t*)outp)[row * N + col] = (bf16_t)(v + resid[row * N + col]);
          } else {
            float g = 0.5f * v * (1.0f + fast_erf(v * 0.70710678118654752f));
            ((bf16_t*)outp)[row * N + col] = (bf16_t)g;
          }
        }
      }
    }
  }
}

// ---------------------------------------------------------------- kv partials WITH fused exp + column-sum.
__global__ __launch_bounds__(256) void kv_partial(const bf16_t* __restrict__ qkv,
                                                  float* __restrict__ kvp,
                                                  float* __restrict__ esump) {
  int bh = blockIdx.x, ch = blockIdx.y;
  int b = bh >> 4, h = bh & 15;
  int t = threadIdx.x;
  __shared__ float Kexp[64][65];
  __shared__ float Vs[64][66];
  int rowl = t >> 2, c0 = (t & 3) * 16;
  int dd = t >> 2, e0 = (t & 3) * 16;
  int lsq = (t & 3) * 16;
  float acc[16] = {};
  float esum = 0.f;
  for (int sb = 0; sb < 8; ++sb) {
    long s = (long)ch * 512 + sb * 64 + rowl;
    const bf16_t* base = qkv + ((long)b * SS + s) * 3072 + h * 64;
    bf16x8 k0 = *(const bf16x8*)(base + 1024 + c0);
    bf16x8 k1 = *(const bf16x8*)(base + 1024 + c0 + 8);
    bf16x8 v0 = *(const bf16x8*)(base + 2048 + c0);
    bf16x8 v1 = *(const bf16x8*)(base + 2048 + c0 + 8);
    __syncthreads();
    #pragma unroll
    for (int j = 0; j < 8; ++j) {
      Kexp[rowl][c0 + j]     = __expf((float)k0[j]);
      Kexp[rowl][c0 + 8 + j] = __expf((float)k1[j]);
      Vs[rowl][c0 + j]       = (float)v0[j];
      Vs[rowl][c0 + 8 + j]   = (float)v1[j];
    }
    __syncthreads();
    for (int ls = 0; ls < 64; ++ls) {
      float kd = Kexp[ls][dd];
      f32x4 va0 = *(const f32x4*)&Vs[ls][e0];
      f32x4 va1 = *(const f32x4*)&Vs[ls][e0 + 4];
      f32x4 va2 = *(const f32x4*)&Vs[ls][e0 + 8];
      f32x4 va3 = *(const f32x4*)&Vs[ls][e0 + 12];
      #pragma unroll
      for (int j = 0; j < 4; ++j) {
        acc[j]      += kd * va0[j];
        acc[j + 4]  += kd * va1[j];
        acc[j + 8]  += kd * va2[j];
        acc[j + 12] += kd * va3[j];
      }
    }
    #pragma unroll
    for (int l2 = 0; l2 < 16; ++l2) esum += Kexp[lsq + l2][dd];
  }
  float* dst = kvp + (long)(bh * 8 + ch) * 4096 + dd * 64 + e0;
  #pragma unroll
  for (int j = 0; j < 16; ++j) dst[j] = acc[j];
  esum += __shfl_xor(esum, 1);
  esum += __shfl_xor(esum, 2);
  if ((t & 3) == 0) esump[(long)(bh * 8 + ch) * 64 + dd] = esum;
}

// reduce partials + normalize, store NATURAL bf16: kvN[bh][d][e]
__global__ void kv_reduce(const float* __restrict__ kvp, const float* __restrict__ esump,
                          bf16_t* __restrict__ kvN) {
  int bh = blockIdx.x, t = threadIdx.x;
  __shared__ float ei[64];
  if (t < 64) {
    float es = 0.f;
    #pragma unroll
    for (int c = 0; c < 8; ++c) es += esump[(long)(bh * 8 + c) * 64 + t];
    ei[t] = 1.0f / es;
  }
  __syncthreads();
  for (int p = t; p < 4096; p += 256) {
    int d = p >> 6;
    float s = 0.f;
    #pragma unroll
    for (int c = 0; c < 8; ++c) s += kvp[(long)(bh * 8 + c) * 4096 + p];
    kvN[(long)bh * 4096 + p] = (bf16_t)(s * ei[d]);
  }
}

// ---------------------------------------------------------------- M[b][j][h*64+d] = sum_e kv[b,h][d,e] * Wout[h*64+e][j]
// = Ws(256j x 64e) @ kvN(64d x 64e)^T per (jt, bh) block.  MBT layout [b][j][hd] (Bt format for q @ M).
__global__ __launch_bounds__(256) void kv_wout(const bf16_t* __restrict__ kvN,
                                               const bf16_t* __restrict__ WT_OUT,
                                               bf16_t* __restrict__ MBT) {
  const int jt = blockIdx.x;          // 0..3
  const int bh = blockIdx.y;          // 0..63
  const int b  = bh >> 4, h = bh & 15;
  const int t = threadIdx.x, lane = t & 63, wave = t >> 6;
  __shared__ bf16_t Ws[256 * 64];
  __shared__ bf16_t Ks[64 * 64];
  const int fr = lane & 15, q4 = lane >> 4, frl = fr & 7;
  const int cr0 = ((q4    ) ^ frl) * 8;
  const int cr1 = ((q4 + 4) ^ frl) * 8;
  #pragma unroll
  for (int p = 0; p < 8; ++p) {
    const int c = t + 256 * p;
    const int row = c >> 3;
    const int gch = ((c & 7) ^ (row & 7)) * 8;
    GLDS16(WT_OUT + (long)(jt * 256 + row) * 1024 + h * 64 + gch, &Ws[c * 8]);
  }
  #pragma unroll
  for (int p = 0; p < 2; ++p) {
    const int c = t + 256 * p;
    const int row = c >> 3;
    const int gch = ((c & 7) ^ (row & 7)) * 8;
    GLDS16(kvN + (long)bh * 4096 + row * 64 + gch, &Ks[c * 8]);
  }
  asm volatile("s_waitcnt vmcnt(0)" ::: "memory");
  __syncthreads();
  f32x4 acc[4][4] = {};
  const int wj = wave * 64;
  {
    bf16x8 a[4], bfr[4];
    #pragma unroll
    for (int i = 0; i < 4; ++i) {
      a[i]   = *(const bf16x8*)&Ws[(wj + i * 16 + fr) * 64 + cr0];
      bfr[i] = *(const bf16x8*)&Ks[(i * 16 + fr) * 64 + cr0];
    }
    #pragma unroll
    for (int i = 0; i < 4; ++i)
      #pragma unroll
      for (int j = 0; j < 4; ++j)
        acc[i][j] = MFMA16(a[i], bfr[j], acc[i][j]);
    #pragma unroll
    for (int i = 0; i < 4; ++i) {
      a[i]   = *(const bf16x8*)&Ws[(wj + i * 16 + fr) * 64 + cr1];
      bfr[i] = *(const bf16x8*)&Ks[(i * 16 + fr) * 64 + cr1];
    }
    #pragma unroll
    for (int i = 0; i < 4; ++i)
      #pragma unroll
      for (int j = 0; j < 4; ++j)
        acc[i][j] = MFMA16(a[i], bfr[j], acc[i][j]);
  }
  const int rq = q4 * 4;
  #pragma unroll
  for (int i = 0; i < 4; ++i)
    #pragma unroll
    for (int j = 0; j < 4; ++j)
      #pragma unroll
      for (int r = 0; r < 4; ++r)
        MBT[((long)b * 1024 + jt * 256 + wj + i * 16 + rq + r) * 1024 + h * 64 + j * 16 + fr]
            = (bf16_t)acc[i][j][r];
}

// ---------------------------------------------------------------- launch
extern "C" void kernel_launch(void* const* d_in, const int* in_sizes, int n_in,
                              void* d_out, int out_size, void* d_ws, size_t ws_size,
                              hipStream_t stream) {
  (void)in_sizes; (void)n_in; (void)out_size;
  const float* x      = (const float*)d_in[0];
  const float* w_qkv  = (const float*)d_in[1];
  const float* b_qkv  = (const float*)d_in[2];
  const float* w_out  = (const float*)d_in[3];
  const float* b_out  = (const float*)d_in[4];
  const float* w_ffn1 = (const float*)d_in[5];
  const float* b_ffn1 = (const float*)d_in[6];
  const float* w_ffn2 = (const float*)d_in[7];
  const float* b_ffn2 = (const float*)d_in[8];
  const float* g1     = (const float*)d_in[9];
  const float* be1    = (const float*)d_in[10];
  const float* g2     = (const float*)d_in[11];
  const float* be2    = (const float*)d_in[12];

  char* ws = (char*)d_ws;
  constexpr size_t WT_QKV_OFF  = 0;
  constexpr size_t WT_OUT_OFF  = WT_QKV_OFF  + 6291456;
  constexpr size_t WT_FFN1_OFF = WT_OUT_OFF  + 2097152;
  constexpr size_t WT_FFN2_OFF = WT_FFN1_OFF + 8388608;
  constexpr size_t ESUMP_OFF   = WT_FFN2_OFF + 8388608;
  constexpr size_t KVP_OFF     = ESUMP_OFF   + 294912;
  constexpr size_t KVN_OFF     = KVP_OFF     + 8388608;
  constexpr size_t MBT_OFF     = KVN_OFF     + 524288;
  constexpr size_t ACT1_OFF    = MBT_OFF     + 8388608;
  constexpr size_t BIG_OFF     = ACT1_OFF    + 33554432;  // 76,316,672

  bf16_t* WT_QKV  = (bf16_t*)(ws + WT_QKV_OFF);
  bf16_t* WT_OUT  = (bf16_t*)(ws + WT_OUT_OFF);
  bf16_t* WT_FFN1 = (bf16_t*)(ws + WT_FFN1_OFF);
  bf16_t* WT_FFN2 = (bf16_t*)(ws + WT_FFN2_OFF);
  float*  ESUMP   = (float*) (ws + ESUMP_OFF);
  float*  KVP     = (float*) (ws + KVP_OFF);
  bf16_t* KVN     = (bf16_t*)(ws + KVN_OFF);
  bf16_t* MBT     = (bf16_t*)(ws + MBT_OFF);
  bf16_t* ACT1    = (bf16_t*)(ws + ACT1_OFF);
  bf16_t* QKV     = (bf16_t*)(ws + BIG_OFF);   // 96 MB
  bf16_t* GACT    = (bf16_t*)(ws + BIG_OFF);   // up to 128 MB, after QKV dead
  bf16_t* YB      = (bf16_t*)d_out;            // y (bf16) lives in d_out; ffn2 overwrites all of d_out (f32)

  const bool big_ws = ws_size >= (size_t)(BIG_OFF + 134217728ull);

  prep_kernel<<<12288 + NROWS, 256, 0, stream>>>(w_qkv, w_out, w_ffn1, w_ffn2,
                                                 WT_QKV, WT_OUT, WT_FFN1, WT_FFN2,
                                                 x, g1, be1, ACT1);

  // qkv = ln1 @ WqkvT + b, q-softmax fused (grid 24 x 128)
  gemm_bt<3><<<dim3(3072 / 128, NROWS / 128), 256, 0, stream>>>(ACT1, WT_QKV, b_qkv, nullptr, QKV,
                                                                NROWS, 3072, 1024, 1024, 0);

  // kv einsum with fused exp + column-sum, then normalize, then fold W_out into per-batch M
  kv_partial<<<dim3(64, 8), 256, 0, stream>>>(QKV, KVP, ESUMP);
  kv_reduce<<<64, 256, 0, stream>>>(KVP, ESUMP, KVN);
  kv_wout<<<dim3(4, 64), 256, 0, stream>>>(KVN, WT_OUT, MBT);

  // y = x + q @ M + b_out  -> YB (bf16, in d_out)   (A = Q region of QKV, lda=3072; per-batch B)
  gemm_bt<4><<<dim3(1024 / 128, NROWS / 128), 256, 0, stream>>>(QKV, MBT, b_out, x, YB,
                                                                NROWS, 1024, 1024, 3072, 1048576);

  // ln2(y) -> ACT1
  ln_bf16<<<NROWS, 256, 0, stream>>>(YB, g2, be2, ACT1);

  if (big_ws) {
    gemm_bt<2><<<dim3(4096 / 128, NROWS / 128), 256, 0, stream>>>(ACT1, WT_FFN1, b_ffn1, nullptr, GACT,
                                                                  NROWS, 4096, 1024, 1024, 0);
    gemm_bt<1><<<dim3(1024 / 128, NROWS / 128), 256, 0, stream>>>(GACT, WT_FFN2, b_ffn2, x, (float*)d_out,
                                                                  NROWS, 1024, 4096, 4096, 0);
  } else {
    for (int c = 0; c < 2; ++c) {
      const long r0 = (long)c * 8192;
      gemm_bt<2><<<dim3(4096 / 128, 8192 / 128), 256, 0, stream>>>(
          ACT1 + r0 * 1024, WT_FFN1, b_ffn1, nullptr, GACT, 8192, 4096, 1024, 1024, 0);
      gemm_bt<1><<<dim3(1024 / 128, 8192 / 128), 256, 0, stream>>>(
          GACT, WT_FFN2, b_ffn2, x + r0 * 1024, (float*)d_out + r0 * 1024, 8192, 1024, 4096, 4096, 0);
    }
  }
}

// Round 20
// 546.310 us; speedup vs baseline: 1.1612x; 1.1104x over previous
//
#include <hip/hip_runtime.h>
#include <hip/hip_bf16.h>
#include <cstdint>
#include <cstddef>

#define DIMC 1024
#define HEADS 16
#define HD 64
#define DFF 4096
#define BB 4
#define SS 4096
#define NROWS (BB*SS)   // 16384

typedef __bf16 bf16_t;
typedef __bf16 bf16x8 __attribute__((ext_vector_type(8)));
typedef __bf16 bf16x4 __attribute__((ext_vector_type(4)));
typedef float  f32x4  __attribute__((ext_vector_type(4)));

#define GLDS16(gp, lp) \
  __builtin_amdgcn_global_load_lds((const __attribute__((address_space(1))) void*)(gp), \
                                   (__attribute__((address_space(3))) void*)(lp), 16, 0, 0)

#define MFMA16(a, b, c) __builtin_amdgcn_mfma_f32_16x16x32_bf16((a), (b), (c), 0, 0, 0)

// fast erf, Abramowitz-Stegun 7.1.26, |abs err| <= 1.5e-7
__device__ __forceinline__ float fast_erf(float x) {
  float ax = fabsf(x);
  float t  = __builtin_amdgcn_rcpf(fmaf(0.3275911f, ax, 1.0f));
  float p  = t * fmaf(t, fmaf(t, fmaf(t, fmaf(t, 1.061405429f, -1.453152027f),
                                      1.421413741f), -0.284496736f), 0.254829592f);
  float er = 1.0f - p * __expf(-ax * ax);
  return copysignf(er, x);
}

// ---------------------------------------------------------------- fused prep: 4x weight transpose + ln1
__global__ __launch_bounds__(256) void prep_kernel(const float* __restrict__ w_qkv,
                                                   const float* __restrict__ w_out,
                                                   const float* __restrict__ w_ffn1,
                                                   const float* __restrict__ w_ffn2,
                                                   bf16_t* __restrict__ WT_QKV,
                                                   bf16_t* __restrict__ WT_OUT,
                                                   bf16_t* __restrict__ WT_FFN1,
                                                   bf16_t* __restrict__ WT_FFN2,
                                                   const float* __restrict__ x,
                                                   const float* __restrict__ gamma,
                                                   const float* __restrict__ beta,
                                                   bf16_t* __restrict__ act1) {
  const int bid = blockIdx.x;
  if (bid < 12288) {
    const float* W; bf16_t* Wt; int K, N, bx, by;
    if (bid < 3072)      { W = w_qkv;  Wt = WT_QKV;  K = 1024; N = 3072; bx = bid % 96;           by = bid / 96; }
    else if (bid < 4096) { W = w_out;  Wt = WT_OUT;  K = 1024; N = 1024; bx = (bid - 3072) % 32;  by = (bid - 3072) / 32; }
    else if (bid < 8192) { W = w_ffn1; Wt = WT_FFN1; K = 1024; N = 4096; bx = (bid - 4096) % 128; by = (bid - 4096) / 128; }
    else                 { W = w_ffn2; Wt = WT_FFN2; K = 4096; N = 1024; bx = (bid - 8192) % 32;  by = (bid - 8192) / 32; }
    __shared__ float tile[32][33];
    const int tx = threadIdx.x & 31, ty = threadIdx.x >> 5;
    const int c0 = bx * 32, r0 = by * 32;
    #pragma unroll
    for (int i = 0; i < 32; i += 8)
      tile[ty + i][tx] = W[(long)(r0 + ty + i) * N + c0 + tx];
    __syncthreads();
    #pragma unroll
    for (int i = 0; i < 32; i += 8)
      Wt[(long)(c0 + ty + i) * K + r0 + tx] = (bf16_t)tile[tx][ty + i];
  } else {
    long r = bid - 12288;
    int t = threadIdx.x;
    float4 v = ((const float4*)(x + r * DIMC))[t];
    float s  = v.x + v.y + v.z + v.w;
    float sq = v.x * v.x + v.y * v.y + v.z * v.z + v.w * v.w;
    #pragma unroll
    for (int o = 32; o > 0; o >>= 1) { s += __shfl_xor(s, o); sq += __shfl_xor(sq, o); }
    __shared__ float red[8];
    if ((t & 63) == 0) { red[(t >> 6) * 2] = s; red[(t >> 6) * 2 + 1] = sq; }
    __syncthreads();
    s  = red[0] + red[2] + red[4] + red[6];
    sq = red[1] + red[3] + red[5] + red[7];
    float mu  = s * (1.0f / DIMC);
    float var = sq * (1.0f / DIMC) - mu * mu;
    float rs  = 1.0f / sqrtf(var + 1e-5f);
    float4 g  = ((const float4*)gamma)[t];
    float4 bb = ((const float4*)beta)[t];
    bf16x4 o;
    o[0] = (bf16_t)((v.x - mu) * rs * g.x + bb.x);
    o[1] = (bf16_t)((v.y - mu) * rs * g.y + bb.y);
    o[2] = (bf16_t)((v.z - mu) * rs * g.z + bb.z);
    o[3] = (bf16_t)((v.w - mu) * rs * g.w + bb.w);
    ((bf16x4*)(act1 + r * DIMC))[t] = o;
  }
}

// ---------------------------------------------------------------- LayerNorm bf16 row -> bf16 row (ln2; y stored bf16)
__global__ __launch_bounds__(256) void ln_bf16(const bf16_t* __restrict__ in,
                                               const float* __restrict__ gamma,
                                               const float* __restrict__ beta,
                                               bf16_t* __restrict__ out) {
  long r = blockIdx.x;
  int t = threadIdx.x;
  bf16x4 v4 = ((const bf16x4*)(in + r * DIMC))[t];
  float v0 = v4[0], v1 = v4[1], v2 = v4[2], v3 = v4[3];
  float s  = v0 + v1 + v2 + v3;
  float sq = v0 * v0 + v1 * v1 + v2 * v2 + v3 * v3;
  #pragma unroll
  for (int o = 32; o > 0; o >>= 1) { s += __shfl_xor(s, o); sq += __shfl_xor(sq, o); }
  __shared__ float red[8];
  if ((t & 63) == 0) { red[(t >> 6) * 2] = s; red[(t >> 6) * 2 + 1] = sq; }
  __syncthreads();
  s  = red[0] + red[2] + red[4] + red[6];
  sq = red[1] + red[3] + red[5] + red[7];
  float mu  = s * (1.0f / DIMC);
  float var = sq * (1.0f / DIMC) - mu * mu;
  float rs  = 1.0f / sqrtf(var + 1e-5f);
  float4 g  = ((const float4*)gamma)[t];
  float4 bb = ((const float4*)beta)[t];
  bf16x4 o;
  o[0] = (bf16_t)((v0 - mu) * rs * g.x + bb.x);
  o[1] = (bf16_t)((v1 - mu) * rs * g.y + bb.y);
  o[2] = (bf16_t)((v2 - mu) * rs * g.z + bb.z);
  o[3] = (bf16_t)((v3 - mu) * rs * g.w + bb.w);
  ((bf16x4*)(out + r * DIMC))[t] = o;
}

// ---------------------------------------------------------------- GEMM: A[M][K](lda) bf16 @ Bt[N][K] bf16 -> epilogue
// 128x128 tile, BK=64, XCD swizzle, XOR LDS swizzle (conflict-free), multi-block/CU.
// Bt may be per-batch (bstride elements per 4096 A-rows).
// MODE 0: bf16 = acc+bias                MODE 1: f32  = acc+bias+resid(f32)
// MODE 2: bf16 = gelu(acc+bias)          MODE 3: bf16 = acc+bias, q-softmax fused for cols<1024
// MODE 4: bf16 = acc+bias+resid(f32)
template <int MODE>
__global__ __launch_bounds__(256, 2) void gemm_bt(const bf16_t* __restrict__ A,
                                                  const bf16_t* __restrict__ Bt,
                                                  const float* __restrict__ bias,
                                                  const float* __restrict__ resid,
                                                  void* __restrict__ outp,
                                                  int M, int N, int K, int lda, long bstride) {
  __shared__ bf16_t As[128 * 64];
  __shared__ bf16_t Bs[128 * 64];
  const int t = threadIdx.x;
  const int lane = t & 63;
  const int wave = t >> 6;

  const int nwg  = gridDim.x * gridDim.y;
  const int bid0 = blockIdx.y * gridDim.x + blockIdx.x;
  const int lg   = (bid0 & 7) * (nwg >> 3) + (bid0 >> 3);
  const int span = (int)gridDim.y << 2;
  const int gidx = lg / span;
  const int rem  = lg - gidx * span;
  const long arow0 = (long)(rem >> 2) * 128;
  const long brow0 = (long)((gidx << 2) + (rem & 3)) * 128;

  const bf16_t* BtB = Bt + (arow0 >> 12) * bstride;

  const int wm = (wave >> 1) * 64, wn = (wave & 1) * 64;

  f32x4 acc[4][4] = {};
  const int fr  = lane & 15;
  const int q4  = lane >> 4;
  const int frl = fr & 7;
  const int cr0 = ((q4    ) ^ frl) * 8;
  const int cr1 = ((q4 + 4) ^ frl) * 8;

  for (int kt = 0; kt < K; kt += 64) {
    #pragma unroll
    for (int p = 0; p < 4; ++p) {
      const int c = t + 256 * p;
      const int row = c >> 3;
      const int gch = ((c & 7) ^ (row & 7)) * 8;
      GLDS16(A   + (arow0 + row) * (long)lda + kt + gch, &As[c * 8]);
      GLDS16(BtB + (brow0 + row) * (long)K   + kt + gch, &Bs[c * 8]);
    }
    asm volatile("s_waitcnt vmcnt(0)" ::: "memory");
    __syncthreads();
    {
      bf16x8 a[4], b[4];
      #pragma unroll
      for (int i = 0; i < 4; ++i) {
        a[i] = *(const bf16x8*)&As[(wm + i * 16 + fr) * 64 + cr0];
        b[i] = *(const bf16x8*)&Bs[(wn + i * 16 + fr) * 64 + cr0];
      }
      #pragma unroll
      for (int i = 0; i < 4; ++i)
        #pragma unroll
        for (int j = 0; j < 4; ++j)
          acc[i][j] = MFMA16(a[i], b[j], acc[i][j]);
      #pragma unroll
      for (int i = 0; i < 4; ++i) {
        a[i] = *(const bf16x8*)&As[(wm + i * 16 + fr) * 64 + cr1];
        b[i] = *(const bf16x8*)&Bs[(wn + i * 16 + fr) * 64 + cr1];
      }
      #pragma unroll
      for (int i = 0; i < 4; ++i)
        #pragma unroll
        for (int j = 0; j < 4; ++j)
          acc[i][j] = MFMA16(a[i], b[j], acc[i][j]);
    }
    __syncthreads();
  }

  const int rq = q4 * 4;

  if (MODE == 3 && brow0 < 1024) {
    float bv[4];
    #pragma unroll
    for (int j = 0; j < 4; ++j) bv[j] = bias[brow0 + wn + j * 16 + fr];
    #pragma unroll
    for (int i = 0; i < 4; ++i) {
      #pragma unroll
      for (int r = 0; r < 4; ++r) {
        float v[4];
        #pragma unroll
        for (int j = 0; j < 4; ++j) v[j] = acc[i][j][r] + bv[j];
        float m = fmaxf(fmaxf(v[0], v[1]), fmaxf(v[2], v[3]));
        #pragma unroll
        for (int o = 1; o <= 8; o <<= 1) m = fmaxf(m, __shfl_xor(m, o));
        float e[4], s = 0.f;
        #pragma unroll
        for (int j = 0; j < 4; ++j) { e[j] = __expf(v[j] - m); s += e[j]; }
        #pragma unroll
        for (int o = 1; o <= 8; o <<= 1) s += __shfl_xor(s, o);
        float inv = 1.0f / s;
        long row = arow0 + wm + i * 16 + rq + r;
        #pragma unroll
        for (int j = 0; j < 4; ++j)
          ((bf16_t*)outp)[row * N + brow0 + wn + j * 16 + fr] = (bf16_t)(e[j] * inv);
      }
    }
  } else {
    #pragma unroll
    for (int i = 0; i < 4; ++i) {
      #pragma unroll
      for (int j = 0; j < 4; ++j) {
        long col = brow0 + wn + j * 16 + fr;
        float bv = bias[col];
        #pragma unroll
        for (int r = 0; r < 4; ++r) {
          long row = arow0 + wm + i * 16 + rq + r;
          float v = acc[i][j][r] + bv;
          if (MODE == 0 || MODE == 3) {
            ((bf16_t*)outp)[row * N + col] = (bf16_t)v;
          } else if (MODE == 1) {
            ((float*)outp)[row * N + col] = v + resid[row * N + col];
          } else if (MODE == 4) {
            ((bf16_t*)outp)[row * N + col] = (bf16_t)(v + resid[row * N + col]);
          } else {
            float g = 0.5f * v * (1.0f + fast_erf(v * 0.70710678118654752f));
            ((bf16_t*)outp)[row * N + col] = (bf16_t)g;
          }
        }
      }
    }
  }
}

// ---------------------------------------------------------------- kv partials via MFMA, all-register (no LDS staging).
// kv[d][e] = sum_s exp(k[s,d]) v[s,e].  A-frag = exp(K) loaded direct into fragment layout,
// B-frag = V likewise; per-wave e-tile, 4 d-tiles; esum accumulated in f32 at exp time.
__global__ __launch_bounds__(256) void kv_partial(const bf16_t* __restrict__ qkv,
                                                  float* __restrict__ kvp,
                                                  float* __restrict__ esump) {
  const int bh = blockIdx.x, ch = blockIdx.y;
  const int b = bh >> 4, h = bh & 15;
  const int t = threadIdx.x, lane = t & 63, w = t >> 6;   // wave = e-tile 0..3
  const int fr = lane & 15, q4 = lane >> 4;

  const bf16_t* kbase = qkv + (long)b * SS * 3072 + 1024 + h * 64;  // k[s][d] @ kbase + s*3072 + d
  const bf16_t* vbase = qkv + (long)b * SS * 3072 + 2048 + h * 64;  // v[s][e]

  f32x4 acc[4] = {};
  float es[4] = {0.f, 0.f, 0.f, 0.f};

  for (int sb = 0; sb < 16; ++sb) {                 // 16 k-steps of 32 s => 512 s per chunk
    const long s0 = (long)ch * 512 + sb * 32 + q4 * 8;
    bf16x8 af[4];
    #pragma unroll
    for (int i = 0; i < 4; ++i) {
      const bf16_t* kp = kbase + s0 * 3072 + i * 16 + fr;
      #pragma unroll
      for (int j = 0; j < 8; ++j) {
        float ex = __expf((float)kp[(long)j * 3072]);
        af[i][j] = (bf16_t)ex;
        es[i] += ex;
      }
    }
    bf16x8 bfv;
    const bf16_t* vp = vbase + s0 * 3072 + w * 16 + fr;
    #pragma unroll
    for (int j = 0; j < 8; ++j) bfv[j] = vp[(long)j * 3072];
    #pragma unroll
    for (int i = 0; i < 4; ++i) acc[i] = MFMA16(af[i], bfv, acc[i]);
  }

  // write partials: C row = d-within-tile = q4*4 + r, col = e = w*16 + fr
  float* dst = kvp + (long)(bh * 8 + ch) * 4096;
  #pragma unroll
  for (int i = 0; i < 4; ++i)
    #pragma unroll
    for (int r = 0; r < 4; ++r)
      dst[(i * 16 + q4 * 4 + r) * 64 + w * 16 + fr] = acc[i][r];

  // esum: fold q4 stripes (lanes L, L^16, L^32); identical across waves -> wave 0 lanes 0..15 write
  #pragma unroll
  for (int i = 0; i < 4; ++i) {
    es[i] += __shfl_xor(es[i], 16);
    es[i] += __shfl_xor(es[i], 32);
  }
  if (t < 16) {
    #pragma unroll
    for (int i = 0; i < 4; ++i)
      esump[(long)(bh * 8 + ch) * 64 + i * 16 + t] = es[i];
  }
}

// reduce partials + normalize, store NATURAL bf16: kvN[bh][d][e]
__global__ void kv_reduce(const float* __restrict__ kvp, const float* __restrict__ esump,
                          bf16_t* __restrict__ kvN) {
  int bh = blockIdx.x, t = threadIdx.x;
  __shared__ float ei[64];
  if (t < 64) {
    float es = 0.f;
    #pragma unroll
    for (int c = 0; c < 8; ++c) es += esump[(long)(bh * 8 + c) * 64 + t];
    ei[t] = 1.0f / es;
  }
  __syncthreads();
  for (int p = t; p < 4096; p += 256) {
    int d = p >> 6;
    float s = 0.f;
    #pragma unroll
    for (int c = 0; c < 8; ++c) s += kvp[(long)(bh * 8 + c) * 4096 + p];
    kvN[(long)bh * 4096 + p] = (bf16_t)(s * ei[d]);
  }
}

// ---------------------------------------------------------------- M[b][j][h*64+d] = sum_e kv[b,h][d,e] * Wout[h*64+e][j]
__global__ __launch_bounds__(256) void kv_wout(const bf16_t* __restrict__ kvN,
                                               const bf16_t* __restrict__ WT_OUT,
                                               bf16_t* __restrict__ MBT) {
  const int jt = blockIdx.x;          // 0..3
  const int bh = blockIdx.y;          // 0..63
  const int b  = bh >> 4, h = bh & 15;
  const int t = threadIdx.x, lane = t & 63, wave = t >> 6;
  __shared__ bf16_t Ws[256 * 64];
  __shared__ bf16_t Ks[64 * 64];
  const int fr = lane & 15, q4 = lane >> 4, frl = fr & 7;
  const int cr0 = ((q4    ) ^ frl) * 8;
  const int cr1 = ((q4 + 4) ^ frl) * 8;
  #pragma unroll
  for (int p = 0; p < 8; ++p) {
    const int c = t + 256 * p;
    const int row = c >> 3;
    const int gch = ((c & 7) ^ (row & 7)) * 8;
    GLDS16(WT_OUT + (long)(jt * 256 + row) * 1024 + h * 64 + gch, &Ws[c * 8]);
  }
  #pragma unroll
  for (int p = 0; p < 2; ++p) {
    const int c = t + 256 * p;
    const int row = c >> 3;
    const int gch = ((c & 7) ^ (row & 7)) * 8;
    GLDS16(kvN + (long)bh * 4096 + row * 64 + gch, &Ks[c * 8]);
  }
  asm volatile("s_waitcnt vmcnt(0)" ::: "memory");
  __syncthreads();
  f32x4 acc[4][4] = {};
  const int wj = wave * 64;
  {
    bf16x8 a[4], bfr[4];
    #pragma unroll
    for (int i = 0; i < 4; ++i) {
      a[i]   = *(const bf16x8*)&Ws[(wj + i * 16 + fr) * 64 + cr0];
      bfr[i] = *(const bf16x8*)&Ks[(i * 16 + fr) * 64 + cr0];
    }
    #pragma unroll
    for (int i = 0; i < 4; ++i)
      #pragma unroll
      for (int j = 0; j < 4; ++j)
        acc[i][j] = MFMA16(a[i], bfr[j], acc[i][j]);
    #pragma unroll
    for (int i = 0; i < 4; ++i) {
      a[i]   = *(const bf16x8*)&Ws[(wj + i * 16 + fr) * 64 + cr1];
      bfr[i] = *(const bf16x8*)&Ks[(i * 16 + fr) * 64 + cr1];
    }
    #pragma unroll
    for (int i = 0; i < 4; ++i)
      #pragma unroll
      for (int j = 0; j < 4; ++j)
        acc[i][j] = MFMA16(a[i], bfr[j], acc[i][j]);
  }
  const int rq = q4 * 4;
  #pragma unroll
  for (int i = 0; i < 4; ++i)
    #pragma unroll
    for (int j = 0; j < 4; ++j)
      #pragma unroll
      for (int r = 0; r < 4; ++r)
        MBT[((long)b * 1024 + jt * 256 + wj + i * 16 + rq + r) * 1024 + h * 64 + j * 16 + fr]
            = (bf16_t)acc[i][j][r];
}

// ---------------------------------------------------------------- launch
extern "C" void kernel_launch(void* const* d_in, const int* in_sizes, int n_in,
                              void* d_out, int out_size, void* d_ws, size_t ws_size,
                              hipStream_t stream) {
  (void)in_sizes; (void)n_in; (void)out_size;
  const float* x      = (const float*)d_in[0];
  const float* w_qkv  = (const float*)d_in[1];
  const float* b_qkv  = (const float*)d_in[2];
  const float* w_out  = (const float*)d_in[3];
  const float* b_out  = (const float*)d_in[4];
  const float* w_ffn1 = (const float*)d_in[5];
  const float* b_ffn1 = (const float*)d_in[6];
  const float* w_ffn2 = (const float*)d_in[7];
  const float* b_ffn2 = (const float*)d_in[8];
  const float* g1     = (const float*)d_in[9];
  const float* be1    = (const float*)d_in[10];
  const float* g2     = (const float*)d_in[11];
  const float* be2    = (const float*)d_in[12];

  char* ws = (char*)d_ws;
  constexpr size_t WT_QKV_OFF  = 0;
  constexpr size_t WT_OUT_OFF  = WT_QKV_OFF  + 6291456;
  constexpr size_t WT_FFN1_OFF = WT_OUT_OFF  + 2097152;
  constexpr size_t WT_FFN2_OFF = WT_FFN1_OFF + 8388608;
  constexpr size_t ESUMP_OFF   = WT_FFN2_OFF + 8388608;
  constexpr size_t KVP_OFF     = ESUMP_OFF   + 294912;
  constexpr size_t KVN_OFF     = KVP_OFF     + 8388608;
  constexpr size_t MBT_OFF     = KVN_OFF     + 524288;
  constexpr size_t ACT1_OFF    = MBT_OFF     + 8388608;
  constexpr size_t BIG_OFF     = ACT1_OFF    + 33554432;  // 76,316,672

  bf16_t* WT_QKV  = (bf16_t*)(ws + WT_QKV_OFF);
  bf16_t* WT_OUT  = (bf16_t*)(ws + WT_OUT_OFF);
  bf16_t* WT_FFN1 = (bf16_t*)(ws + WT_FFN1_OFF);
  bf16_t* WT_FFN2 = (bf16_t*)(ws + WT_FFN2_OFF);
  float*  ESUMP   = (float*) (ws + ESUMP_OFF);
  float*  KVP     = (float*) (ws + KVP_OFF);
  bf16_t* KVN     = (bf16_t*)(ws + KVN_OFF);
  bf16_t* MBT     = (bf16_t*)(ws + MBT_OFF);
  bf16_t* ACT1    = (bf16_t*)(ws + ACT1_OFF);
  bf16_t* QKV     = (bf16_t*)(ws + BIG_OFF);   // 96 MB
  bf16_t* GACT    = (bf16_t*)(ws + BIG_OFF);   // up to 128 MB, after QKV dead
  bf16_t* YB      = (bf16_t*)d_out;            // y (bf16) lives in d_out; ffn2 overwrites all of d_out (f32)

  const bool big_ws = ws_size >= (size_t)(BIG_OFF + 134217728ull);

  prep_kernel<<<12288 + NROWS, 256, 0, stream>>>(w_qkv, w_out, w_ffn1, w_ffn2,
                                                 WT_QKV, WT_OUT, WT_FFN1, WT_FFN2,
                                                 x, g1, be1, ACT1);

  // qkv = ln1 @ WqkvT + b, q-softmax fused (grid 24 x 128)
  gemm_bt<3><<<dim3(3072 / 128, NROWS / 128), 256, 0, stream>>>(ACT1, WT_QKV, b_qkv, nullptr, QKV,
                                                                NROWS, 3072, 1024, 1024, 0);

  // kv einsum (MFMA, fused exp + column-sum), normalize, fold W_out into per-batch M
  kv_partial<<<dim3(64, 8), 256, 0, stream>>>(QKV, KVP, ESUMP);
  kv_reduce<<<64, 256, 0, stream>>>(KVP, ESUMP, KVN);
  kv_wout<<<dim3(4, 64), 256, 0, stream>>>(KVN, WT_OUT, MBT);

  // y = x + q @ M + b_out  -> YB (bf16, in d_out)   (A = Q region of QKV, lda=3072; per-batch B)
  gemm_bt<4><<<dim3(1024 / 128, NROWS / 128), 256, 0, stream>>>(QKV, MBT, b_out, x, YB,
                                                                NROWS, 1024, 1024, 3072, 1048576);

  // ln2(y) -> ACT1
  ln_bf16<<<NROWS, 256, 0, stream>>>(YB, g2, be2, ACT1);

  if (big_ws) {
    gemm_bt<2><<<dim3(4096 / 128, NROWS / 128), 256, 0, stream>>>(ACT1, WT_FFN1, b_ffn1, nullptr, GACT,
                                                                  NROWS, 4096, 1024, 1024, 0);
    gemm_bt<1><<<dim3(1024 / 128, NROWS / 128), 256, 0, stream>>>(GACT, WT_FFN2, b_ffn2, x, (float*)d_out,
                                                                  NROWS, 1024, 4096, 4096, 0);
  } else {
    for (int c = 0; c < 2; ++c) {
      const long r0 = (long)c * 8192;
      gemm_bt<2><<<dim3(4096 / 128, 8192 / 128), 256, 0, stream>>>(
          ACT1 + r0 * 1024, WT_FFN1, b_ffn1, nullptr, GACT, 8192, 4096, 1024, 1024, 0);
      gemm_bt<1><<<dim3(1024 / 128, 8192 / 128), 256, 0, stream>>>(
          GACT, WT_FFN2, b_ffn2, x + r0 * 1024, (float*)d_out + r0 * 1024, 8192, 1024, 4096, 4096, 0);
    }
  }
}

// Round 21
// 545.825 us; speedup vs baseline: 1.1623x; 1.0009x over previous
//
#include <hip/hip_runtime.h>
#include <hip/hip_bf16.h>
#include <cstdint>
#include <cstddef>

#define DIMC 1024
#define HEADS 16
#define HD 64
#define DFF 4096
#define BB 4
#define SS 4096
#define NROWS (BB*SS)   // 16384

typedef __bf16 bf16_t;
typedef __bf16 bf16x8 __attribute__((ext_vector_type(8)));
typedef __bf16 bf16x4 __attribute__((ext_vector_type(4)));
typedef float  f32x4  __attribute__((ext_vector_type(4)));

#define GLDS16(gp, lp) \
  __builtin_amdgcn_global_load_lds((const __attribute__((address_space(1))) void*)(gp), \
                                   (__attribute__((address_space(3))) void*)(lp), 16, 0, 0)

#define MFMA16(a, b, c) __builtin_amdgcn_mfma_f32_16x16x32_bf16((a), (b), (c), 0, 0, 0)

// fast erf, Abramowitz-Stegun 7.1.26, |abs err| <= 1.5e-7
__device__ __forceinline__ float fast_erf(float x) {
  float ax = fabsf(x);
  float t  = __builtin_amdgcn_rcpf(fmaf(0.3275911f, ax, 1.0f));
  float p  = t * fmaf(t, fmaf(t, fmaf(t, fmaf(t, 1.061405429f, -1.453152027f),
                                      1.421413741f), -0.284496736f), 0.254829592f);
  float er = 1.0f - p * __expf(-ax * ax);
  return copysignf(er, x);
}

// ---------------------------------------------------------------- fused prep: 4x weight transpose + ln1
__global__ __launch_bounds__(256) void prep_kernel(const float* __restrict__ w_qkv,
                                                   const float* __restrict__ w_out,
                                                   const float* __restrict__ w_ffn1,
                                                   const float* __restrict__ w_ffn2,
                                                   bf16_t* __restrict__ WT_QKV,
                                                   bf16_t* __restrict__ WT_OUT,
                                                   bf16_t* __restrict__ WT_FFN1,
                                                   bf16_t* __restrict__ WT_FFN2,
                                                   const float* __restrict__ x,
                                                   const float* __restrict__ gamma,
                                                   const float* __restrict__ beta,
                                                   bf16_t* __restrict__ act1) {
  const int bid = blockIdx.x;
  if (bid < 12288) {
    const float* W; bf16_t* Wt; int K, N, bx, by;
    if (bid < 3072)      { W = w_qkv;  Wt = WT_QKV;  K = 1024; N = 3072; bx = bid % 96;           by = bid / 96; }
    else if (bid < 4096) { W = w_out;  Wt = WT_OUT;  K = 1024; N = 1024; bx = (bid - 3072) % 32;  by = (bid - 3072) / 32; }
    else if (bid < 8192) { W = w_ffn1; Wt = WT_FFN1; K = 1024; N = 4096; bx = (bid - 4096) % 128; by = (bid - 4096) / 128; }
    else                 { W = w_ffn2; Wt = WT_FFN2; K = 4096; N = 1024; bx = (bid - 8192) % 32;  by = (bid - 8192) / 32; }
    __shared__ float tile[32][33];
    const int tx = threadIdx.x & 31, ty = threadIdx.x >> 5;
    const int c0 = bx * 32, r0 = by * 32;
    #pragma unroll
    for (int i = 0; i < 32; i += 8)
      tile[ty + i][tx] = W[(long)(r0 + ty + i) * N + c0 + tx];
    __syncthreads();
    #pragma unroll
    for (int i = 0; i < 32; i += 8)
      Wt[(long)(c0 + ty + i) * K + r0 + tx] = (bf16_t)tile[tx][ty + i];
  } else {
    long r = bid - 12288;
    int t = threadIdx.x;
    float4 v = ((const float4*)(x + r * DIMC))[t];
    float s  = v.x + v.y + v.z + v.w;
    float sq = v.x * v.x + v.y * v.y + v.z * v.z + v.w * v.w;
    #pragma unroll
    for (int o = 32; o > 0; o >>= 1) { s += __shfl_xor(s, o); sq += __shfl_xor(sq, o); }
    __shared__ float red[8];
    if ((t & 63) == 0) { red[(t >> 6) * 2] = s; red[(t >> 6) * 2 + 1] = sq; }
    __syncthreads();
    s  = red[0] + red[2] + red[4] + red[6];
    sq = red[1] + red[3] + red[5] + red[7];
    float mu  = s * (1.0f / DIMC);
    float var = sq * (1.0f / DIMC) - mu * mu;
    float rs  = 1.0f / sqrtf(var + 1e-5f);
    float4 g  = ((const float4*)gamma)[t];
    float4 bb = ((const float4*)beta)[t];
    bf16x4 o;
    o[0] = (bf16_t)((v.x - mu) * rs * g.x + bb.x);
    o[1] = (bf16_t)((v.y - mu) * rs * g.y + bb.y);
    o[2] = (bf16_t)((v.z - mu) * rs * g.z + bb.z);
    o[3] = (bf16_t)((v.w - mu) * rs * g.w + bb.w);
    ((bf16x4*)(act1 + r * DIMC))[t] = o;
  }
}

// ---------------------------------------------------------------- LayerNorm bf16 row -> bf16 row (ln2; y stored bf16)
__global__ __launch_bounds__(256) void ln_bf16(const bf16_t* __restrict__ in,
                                               const float* __restrict__ gamma,
                                               const float* __restrict__ beta,
                                               bf16_t* __restrict__ out) {
  long r = blockIdx.x;
  int t = threadIdx.x;
  bf16x4 v4 = ((const bf16x4*)(in + r * DIMC))[t];
  float v0 = v4[0], v1 = v4[1], v2 = v4[2], v3 = v4[3];
  float s  = v0 + v1 + v2 + v3;
  float sq = v0 * v0 + v1 * v1 + v2 * v2 + v3 * v3;
  #pragma unroll
  for (int o = 32; o > 0; o >>= 1) { s += __shfl_xor(s, o); sq += __shfl_xor(sq, o); }
  __shared__ float red[8];
  if ((t & 63) == 0) { red[(t >> 6) * 2] = s; red[(t >> 6) * 2 + 1] = sq; }
  __syncthreads();
  s  = red[0] + red[2] + red[4] + red[6];
  sq = red[1] + red[3] + red[5] + red[7];
  float mu  = s * (1.0f / DIMC);
  float var = sq * (1.0f / DIMC) - mu * mu;
  float rs  = 1.0f / sqrtf(var + 1e-5f);
  float4 g  = ((const float4*)gamma)[t];
  float4 bb = ((const float4*)beta)[t];
  bf16x4 o;
  o[0] = (bf16_t)((v0 - mu) * rs * g.x + bb.x);
  o[1] = (bf16_t)((v1 - mu) * rs * g.y + bb.y);
  o[2] = (bf16_t)((v2 - mu) * rs * g.z + bb.z);
  o[3] = (bf16_t)((v3 - mu) * rs * g.w + bb.w);
  ((bf16x4*)(out + r * DIMC))[t] = o;
}

// ---------------------------------------------------------------- GEMM: A[M][K](lda) bf16 @ Bt[N][K] bf16 -> epilogue
// 128x128 tile, BK=64, XCD swizzle, XOR LDS swizzle (conflict-free), multi-block/CU.
// Bt may be per-batch (bstride elements per 4096 A-rows).
// MODE 0: bf16 = acc+bias                MODE 1: f32  = acc+bias+resid(f32)
// MODE 2: bf16 = gelu(acc+bias)          MODE 3: bf16 = acc+bias, q-softmax fused for cols<1024 -> outp2 (compact 1024-wide)
// MODE 4: bf16 = acc+bias+resid(f32)
template <int MODE>
__global__ __launch_bounds__(256, 2) void gemm_bt(const bf16_t* __restrict__ A,
                                                  const bf16_t* __restrict__ Bt,
                                                  const float* __restrict__ bias,
                                                  const float* __restrict__ resid,
                                                  void* __restrict__ outp,
                                                  void* __restrict__ outp2,
                                                  int M, int N, int K, int lda, long bstride) {
  __shared__ bf16_t As[128 * 64];
  __shared__ bf16_t Bs[128 * 64];
  const int t = threadIdx.x;
  const int lane = t & 63;
  const int wave = t >> 6;

  const int nwg  = gridDim.x * gridDim.y;
  const int bid0 = blockIdx.y * gridDim.x + blockIdx.x;
  const int lg   = (bid0 & 7) * (nwg >> 3) + (bid0 >> 3);
  const int span = (int)gridDim.y << 2;
  const int gidx = lg / span;
  const int rem  = lg - gidx * span;
  const long arow0 = (long)(rem >> 2) * 128;
  const long brow0 = (long)((gidx << 2) + (rem & 3)) * 128;

  const bf16_t* BtB = Bt + (arow0 >> 12) * bstride;

  const int wm = (wave >> 1) * 64, wn = (wave & 1) * 64;

  f32x4 acc[4][4] = {};
  const int fr  = lane & 15;
  const int q4  = lane >> 4;
  const int frl = fr & 7;
  const int cr0 = ((q4    ) ^ frl) * 8;
  const int cr1 = ((q4 + 4) ^ frl) * 8;

  for (int kt = 0; kt < K; kt += 64) {
    #pragma unroll
    for (int p = 0; p < 4; ++p) {
      const int c = t + 256 * p;
      const int row = c >> 3;
      const int gch = ((c & 7) ^ (row & 7)) * 8;
      GLDS16(A   + (arow0 + row) * (long)lda + kt + gch, &As[c * 8]);
      GLDS16(BtB + (brow0 + row) * (long)K   + kt + gch, &Bs[c * 8]);
    }
    asm volatile("s_waitcnt vmcnt(0)" ::: "memory");
    __syncthreads();
    {
      bf16x8 a[4], b[4];
      #pragma unroll
      for (int i = 0; i < 4; ++i) {
        a[i] = *(const bf16x8*)&As[(wm + i * 16 + fr) * 64 + cr0];
        b[i] = *(const bf16x8*)&Bs[(wn + i * 16 + fr) * 64 + cr0];
      }
      #pragma unroll
      for (int i = 0; i < 4; ++i)
        #pragma unroll
        for (int j = 0; j < 4; ++j)
          acc[i][j] = MFMA16(a[i], b[j], acc[i][j]);
      #pragma unroll
      for (int i = 0; i < 4; ++i) {
        a[i] = *(const bf16x8*)&As[(wm + i * 16 + fr) * 64 + cr1];
        b[i] = *(const bf16x8*)&Bs[(wn + i * 16 + fr) * 64 + cr1];
      }
      #pragma unroll
      for (int i = 0; i < 4; ++i)
        #pragma unroll
        for (int j = 0; j < 4; ++j)
          acc[i][j] = MFMA16(a[i], b[j], acc[i][j]);
    }
    __syncthreads();
  }

  const int rq = q4 * 4;

  if (MODE == 3 && brow0 < 1024) {
    // fused q-softmax -> compact Q buffer (row stride 1024)
    float bv[4];
    #pragma unroll
    for (int j = 0; j < 4; ++j) bv[j] = bias[brow0 + wn + j * 16 + fr];
    #pragma unroll
    for (int i = 0; i < 4; ++i) {
      #pragma unroll
      for (int r = 0; r < 4; ++r) {
        float v[4];
        #pragma unroll
        for (int j = 0; j < 4; ++j) v[j] = acc[i][j][r] + bv[j];
        float m = fmaxf(fmaxf(v[0], v[1]), fmaxf(v[2], v[3]));
        #pragma unroll
        for (int o = 1; o <= 8; o <<= 1) m = fmaxf(m, __shfl_xor(m, o));
        float e[4], s = 0.f;
        #pragma unroll
        for (int j = 0; j < 4; ++j) { e[j] = __expf(v[j] - m); s += e[j]; }
        #pragma unroll
        for (int o = 1; o <= 8; o <<= 1) s += __shfl_xor(s, o);
        float inv = 1.0f / s;
        long row = arow0 + wm + i * 16 + rq + r;
        #pragma unroll
        for (int j = 0; j < 4; ++j)
          ((bf16_t*)outp2)[row * 1024 + brow0 + wn + j * 16 + fr] = (bf16_t)(e[j] * inv);
      }
    }
  } else {
    #pragma unroll
    for (int i = 0; i < 4; ++i) {
      #pragma unroll
      for (int j = 0; j < 4; ++j) {
        long col = brow0 + wn + j * 16 + fr;
        float bv = bias[col];
        #pragma unroll
        for (int r = 0; r < 4; ++r) {
          long row = arow0 + wm + i * 16 + rq + r;
          float v = acc[i][j][r] + bv;
          if (MODE == 0 || MODE == 3) {
            ((bf16_t*)outp)[row * N + col] = (bf16_t)v;
          } else if (MODE == 1) {
            ((float*)outp)[row * N + col] = v + resid[row * N + col];
          } else if (MODE == 4) {
            ((bf16_t*)outp)[row * N + col] = (bf16_t)(v + resid[row * N + col]);
          } else {
            float g = 0.5f * v * (1.0f + fast_erf(v * 0.70710678118654752f));
            ((bf16_t*)outp)[row * N + col] = (bf16_t)g;
          }
        }
      }
    }
  }
}

// ---------------------------------------------------------------- kv partials via MFMA, all-register (no LDS staging).
__global__ __launch_bounds__(256) void kv_partial(const bf16_t* __restrict__ qkv,
                                                  float* __restrict__ kvp,
                                                  float* __restrict__ esump) {
  const int bh = blockIdx.x, ch = blockIdx.y;
  const int b = bh >> 4, h = bh & 15;
  const int t = threadIdx.x, lane = t & 63, w = t >> 6;   // wave = e-tile 0..3
  const int fr = lane & 15, q4 = lane >> 4;

  const bf16_t* kbase = qkv + (long)b * SS * 3072 + 1024 + h * 64;
  const bf16_t* vbase = qkv + (long)b * SS * 3072 + 2048 + h * 64;

  f32x4 acc[4] = {};
  float es[4] = {0.f, 0.f, 0.f, 0.f};

  for (int sb = 0; sb < 16; ++sb) {
    const long s0 = (long)ch * 512 + sb * 32 + q4 * 8;
    bf16x8 af[4];
    #pragma unroll
    for (int i = 0; i < 4; ++i) {
      const bf16_t* kp = kbase + s0 * 3072 + i * 16 + fr;
      #pragma unroll
      for (int j = 0; j < 8; ++j) {
        float ex = __expf((float)kp[(long)j * 3072]);
        af[i][j] = (bf16_t)ex;
        es[i] += ex;
      }
    }
    bf16x8 bfv;
    const bf16_t* vp = vbase + s0 * 3072 + w * 16 + fr;
    #pragma unroll
    for (int j = 0; j < 8; ++j) bfv[j] = vp[(long)j * 3072];
    #pragma unroll
    for (int i = 0; i < 4; ++i) acc[i] = MFMA16(af[i], bfv, acc[i]);
  }

  float* dst = kvp + (long)(bh * 8 + ch) * 4096;
  #pragma unroll
  for (int i = 0; i < 4; ++i)
    #pragma unroll
    for (int r = 0; r < 4; ++r)
      dst[(i * 16 + q4 * 4 + r) * 64 + w * 16 + fr] = acc[i][r];

  #pragma unroll
  for (int i = 0; i < 4; ++i) {
    es[i] += __shfl_xor(es[i], 16);
    es[i] += __shfl_xor(es[i], 32);
  }
  if (t < 16) {
    #pragma unroll
    for (int i = 0; i < 4; ++i)
      esump[(long)(bh * 8 + ch) * 64 + i * 16 + t] = es[i];
  }
}

// reduce partials + normalize, store NATURAL bf16: kvN[bh][d][e]
__global__ void kv_reduce(const float* __restrict__ kvp, const float* __restrict__ esump,
                          bf16_t* __restrict__ kvN) {
  int bh = blockIdx.x, t = threadIdx.x;
  __shared__ float ei[64];
  if (t < 64) {
    float es = 0.f;
    #pragma unroll
    for (int c = 0; c < 8; ++c) es += esump[(long)(bh * 8 + c) * 64 + t];
    ei[t] = 1.0f / es;
  }
  __syncthreads();
  for (int p = t; p < 4096; p += 256) {
    int d = p >> 6;
    float s = 0.f;
    #pragma unroll
    for (int c = 0; c < 8; ++c) s += kvp[(long)(bh * 8 + c) * 4096 + p];
    kvN[(long)bh * 4096 + p] = (bf16_t)(s * ei[d]);
  }
}

// ---------------------------------------------------------------- M[b][j][h*64+d] = sum_e kv[b,h][d,e] * Wout[h*64+e][j]
__global__ __launch_bounds__(256) void kv_wout(const bf16_t* __restrict__ kvN,
                                               const bf16_t* __restrict__ WT_OUT,
                                               bf16_t* __restrict__ MBT) {
  const int jt = blockIdx.x;          // 0..3
  const int bh = blockIdx.y;          // 0..63
  const int b  = bh >> 4, h = bh & 15;
  const int t = threadIdx.x, lane = t & 63, wave = t >> 6;
  __shared__ bf16_t Ws[256 * 64];
  __shared__ bf16_t Ks[64 * 64];
  const int fr = lane & 15, q4 = lane >> 4, frl = fr & 7;
  const int cr0 = ((q4    ) ^ frl) * 8;
  const int cr1 = ((q4 + 4) ^ frl) * 8;
  #pragma unroll
  for (int p = 0; p < 8; ++p) {
    const int c = t + 256 * p;
    const int row = c >> 3;
    const int gch = ((c & 7) ^ (row & 7)) * 8;
    GLDS16(WT_OUT + (long)(jt * 256 + row) * 1024 + h * 64 + gch, &Ws[c * 8]);
  }
  #pragma unroll
  for (int p = 0; p < 2; ++p) {
    const int c = t + 256 * p;
    const int row = c >> 3;
    const int gch = ((c & 7) ^ (row & 7)) * 8;
    GLDS16(kvN + (long)bh * 4096 + row * 64 + gch, &Ks[c * 8]);
  }
  asm volatile("s_waitcnt vmcnt(0)" ::: "memory");
  __syncthreads();
  f32x4 acc[4][4] = {};
  const int wj = wave * 64;
  {
    bf16x8 a[4], bfr[4];
    #pragma unroll
    for (int i = 0; i < 4; ++i) {
      a[i]   = *(const bf16x8*)&Ws[(wj + i * 16 + fr) * 64 + cr0];
      bfr[i] = *(const bf16x8*)&Ks[(i * 16 + fr) * 64 + cr0];
    }
    #pragma unroll
    for (int i = 0; i < 4; ++i)
      #pragma unroll
      for (int j = 0; j < 4; ++j)
        acc[i][j] = MFMA16(a[i], bfr[j], acc[i][j]);
    #pragma unroll
    for (int i = 0; i < 4; ++i) {
      a[i]   = *(const bf16x8*)&Ws[(wj + i * 16 + fr) * 64 + cr1];
      bfr[i] = *(const bf16x8*)&Ks[(i * 16 + fr) * 64 + cr1];
    }
    #pragma unroll
    for (int i = 0; i < 4; ++i)
      #pragma unroll
      for (int j = 0; j < 4; ++j)
        acc[i][j] = MFMA16(a[i], bfr[j], acc[i][j]);
  }
  const int rq = q4 * 4;
  #pragma unroll
  for (int i = 0; i < 4; ++i)
    #pragma unroll
    for (int j = 0; j < 4; ++j)
      #pragma unroll
      for (int r = 0; r < 4; ++r)
        MBT[((long)b * 1024 + jt * 256 + wj + i * 16 + rq + r) * 1024 + h * 64 + j * 16 + fr]
            = (bf16_t)acc[i][j][r];
}

// ---------------------------------------------------------------- launch
extern "C" void kernel_launch(void* const* d_in, const int* in_sizes, int n_in,
                              void* d_out, int out_size, void* d_ws, size_t ws_size,
                              hipStream_t stream) {
  (void)in_sizes; (void)n_in; (void)out_size;
  const float* x      = (const float*)d_in[0];
  const float* w_qkv  = (const float*)d_in[1];
  const float* b_qkv  = (const float*)d_in[2];
  const float* w_out  = (const float*)d_in[3];
  const float* b_out  = (const float*)d_in[4];
  const float* w_ffn1 = (const float*)d_in[5];
  const float* b_ffn1 = (const float*)d_in[6];
  const float* w_ffn2 = (const float*)d_in[7];
  const float* b_ffn2 = (const float*)d_in[8];
  const float* g1     = (const float*)d_in[9];
  const float* be1    = (const float*)d_in[10];
  const float* g2     = (const float*)d_in[11];
  const float* be2    = (const float*)d_in[12];

  char* ws = (char*)d_ws;
  constexpr size_t WT_QKV_OFF  = 0;
  constexpr size_t WT_OUT_OFF  = WT_QKV_OFF  + 6291456;
  constexpr size_t WT_FFN1_OFF = WT_OUT_OFF  + 2097152;
  constexpr size_t WT_FFN2_OFF = WT_FFN1_OFF + 8388608;
  constexpr size_t ESUMP_OFF   = WT_FFN2_OFF + 8388608;
  constexpr size_t KVP_OFF     = ESUMP_OFF   + 294912;
  constexpr size_t KVN_OFF     = KVP_OFF     + 8388608;
  constexpr size_t MBT_OFF     = KVN_OFF     + 524288;
  constexpr size_t ACT1_OFF    = MBT_OFF     + 8388608;
  constexpr size_t BIG_OFF     = ACT1_OFF    + 33554432;  // 76,316,672

  bf16_t* WT_QKV  = (bf16_t*)(ws + WT_QKV_OFF);
  bf16_t* WT_OUT  = (bf16_t*)(ws + WT_OUT_OFF);
  bf16_t* WT_FFN1 = (bf16_t*)(ws + WT_FFN1_OFF);
  bf16_t* WT_FFN2 = (bf16_t*)(ws + WT_FFN2_OFF);
  float*  ESUMP   = (float*) (ws + ESUMP_OFF);
  float*  KVP     = (float*) (ws + KVP_OFF);
  bf16_t* KVN     = (bf16_t*)(ws + KVN_OFF);
  bf16_t* MBT     = (bf16_t*)(ws + MBT_OFF);
  bf16_t* ACT1    = (bf16_t*)(ws + ACT1_OFF);
  bf16_t* QKV     = (bf16_t*)(ws + BIG_OFF);                 // 96 MB (K/V live; Q region unused)
  bf16_t* QC      = (bf16_t*)(ws + BIG_OFF + 100663296ull);  // 32 MB compact Q; dead before GACT reaches it
  bf16_t* GACT    = (bf16_t*)(ws + BIG_OFF);                 // up to 128 MB, after QKV/QC dead
  bf16_t* YB      = (bf16_t*)d_out;            // y (bf16) lives in d_out; ffn2 overwrites all of d_out (f32)

  const bool big_ws = ws_size >= (size_t)(BIG_OFF + 134217728ull);

  prep_kernel<<<12288 + NROWS, 256, 0, stream>>>(w_qkv, w_out, w_ffn1, w_ffn2,
                                                 WT_QKV, WT_OUT, WT_FFN1, WT_FFN2,
                                                 x, g1, be1, ACT1);

  // qkv = ln1 @ WqkvT + b; q-softmax fused, Q -> compact QC, K/V -> QKV (grid 24 x 128)
  gemm_bt<3><<<dim3(3072 / 128, NROWS / 128), 256, 0, stream>>>(ACT1, WT_QKV, b_qkv, nullptr, QKV, QC,
                                                                NROWS, 3072, 1024, 1024, 0);

  // kv einsum (MFMA, fused exp + column-sum), normalize, fold W_out into per-batch M
  kv_partial<<<dim3(64, 8), 256, 0, stream>>>(QKV, KVP, ESUMP);
  kv_reduce<<<64, 256, 0, stream>>>(KVP, ESUMP, KVN);
  kv_wout<<<dim3(4, 64), 256, 0, stream>>>(KVN, WT_OUT, MBT);

  // y = x + q @ M + b_out  -> YB (bf16, in d_out)   (A = compact QC, lda=1024; per-batch B)
  gemm_bt<4><<<dim3(1024 / 128, NROWS / 128), 256, 0, stream>>>(QC, MBT, b_out, x, YB, nullptr,
                                                                NROWS, 1024, 1024, 1024, 1048576);

  // ln2(y) -> ACT1
  ln_bf16<<<NROWS, 256, 0, stream>>>(YB, g2, be2, ACT1);

  if (big_ws) {
    gemm_bt<2><<<dim3(4096 / 128, NROWS / 128), 256, 0, stream>>>(ACT1, WT_FFN1, b_ffn1, nullptr, GACT, nullptr,
                                                                  NROWS, 4096, 1024, 1024, 0);
    gemm_bt<1><<<dim3(1024 / 128, NROWS / 128), 256, 0, stream>>>(GACT, WT_FFN2, b_ffn2, x, (float*)d_out, nullptr,
                                                                  NROWS, 1024, 4096, 4096, 0);
  } else {
    for (int c = 0; c < 2; ++c) {
      const long r0 = (long)c * 8192;
      gemm_bt<2><<<dim3(4096 / 128, 8192 / 128), 256, 0, stream>>>(
          ACT1 + r0 * 1024, WT_FFN1, b_ffn1, nullptr, GACT, nullptr, 8192, 4096, 1024, 1024, 0);
      gemm_bt<1><<<dim3(1024 / 128, 8192 / 128), 256, 0, stream>>>(
          GACT, WT_FFN2, b_ffn2, x + r0 * 1024, (float*)d_out + r0 * 1024, nullptr, 8192, 1024, 4096, 4096, 0);
    }
  }
}